// Round 3
// baseline (17371.901 us; speedup 1.0000x reference)
//
#include <hip/hip_runtime.h>
#include <hip/hip_bf16.h>

// Problem constants (S,B,D,H,T) = (4,512,256,1024,50)
#define S_ 4
#define B_ 512
#define D_ 256
#define H_ 1024
#define T_ 50
#define M_ (S_*B_)   // 2048 rows total

typedef __attribute__((ext_vector_type(8))) __bf16 bf16x8;
typedef __attribute__((ext_vector_type(4))) float  f32x4;
typedef __attribute__((ext_vector_type(8))) unsigned short u16x8;

// NaN-free fast tanh: saturates to +/-1, ~1e-6 abs error (<< bf16 eps)
__device__ __forceinline__ float fast_tanh(float x) {
  const float e = __expf(2.f * x);
  return 1.f - 2.f / (e + 1.f);
}

// ---------------------------------------------------------------------------
// Runtime dtype detection + dt table (verified working in round 2).
//   flags[0] = weights/first_point/output are f32 (1) or bf16 (0)
//   flags[1] = time grid is f32 (1) or bf16 (0)
// ---------------------------------------------------------------------------
__global__ void detect_k(const void* t_raw, const void* w2_raw,
                         float* dts, int* flags) {
  __shared__ int cnt;
  const int l = threadIdx.x;           // 64 threads, 1 block
  if (l == 0) cnt = 0;
  __syncthreads();
  const unsigned short* u = (const unsigned short*)w2_raw;
  int c = 0;
  #pragma unroll
  for (int j = 0; j < 4; ++j) {
    const unsigned short v = u[l * 4 + j];
    const unsigned e = (v >> 7) & 0xFF;          // bf16 exponent field
    if (e >= 128) c++;                            // |x| >= 2.0 or NaN/Inf
  }
  atomicAdd(&cnt, c);
  __syncthreads();
  const unsigned tw0 = *(const unsigned*)t_raw;
  const int t_is_f32 = (tw0 == 0u) ? 1 : 0;
  const int w_is_f32 = (cnt > 16) ? 1 : 0;
  if (l == 0) { flags[0] = w_is_f32; flags[1] = t_is_f32; }
  if (l < T_ - 1) {
    float t0, t1;
    if (t_is_f32) {
      const float* tf = (const float*)t_raw;
      t0 = tf[l]; t1 = tf[l + 1];
    } else {
      const __hip_bfloat16* tb = (const __hip_bfloat16*)t_raw;
      t0 = __bfloat162float(tb[l]); t1 = __bfloat162float(tb[l + 1]);
    }
    dts[l] = t1 - t0;
  }
}

// ---------------------------------------------------------------------------
// transpose to bf16: dst[N][K] = bf16(src[K][N]); src dtype per flags[0]
// ---------------------------------------------------------------------------
__global__ void transpose_k(const void* __restrict__ src,
                            __hip_bfloat16* __restrict__ dst, int K, int N,
                            const int* __restrict__ flags) {
  __shared__ __hip_bfloat16 tile[32][33];
  const int f32 = flags[0];
  const int tx = threadIdx.x, ty = threadIdx.y;
  const int nb = blockIdx.x * 32, kb = blockIdx.y * 32;
  #pragma unroll
  for (int j = 0; j < 32; j += 8) {
    const size_t si = (size_t)(kb + ty + j) * N + nb + tx;
    tile[ty + j][tx] = f32 ? __float2bfloat16(((const float*)src)[si])
                           : ((const __hip_bfloat16*)src)[si];
  }
  __syncthreads();
  #pragma unroll
  for (int j = 0; j < 32; j += 8)
    dst[(size_t)(nb + ty + j) * K + kb + tx] = tile[tx][ty + j];
}

// ---------------------------------------------------------------------------
// biases -> fp32 workspace arrays; also zero reg_state tail of out
// ---------------------------------------------------------------------------
__global__ void prep_bias_k(const void* b1r, const void* b2r, const void* b3r,
                            float* bf1, float* bf2, float* bf3,
                            void* out, const int* flags) {
  const int i = blockIdx.x * 256 + threadIdx.x;   // H_ threads
  const int f32 = flags[0];
  bf1[i] = f32 ? ((const float*)b1r)[i]
               : __bfloat162float(((const __hip_bfloat16*)b1r)[i]);
  bf2[i] = f32 ? ((const float*)b2r)[i]
               : __bfloat162float(((const __hip_bfloat16*)b2r)[i]);
  if (i < D_)
    bf3[i] = f32 ? ((const float*)b3r)[i]
                 : __bfloat162float(((const __hip_bfloat16*)b3r)[i]);
  if (i < S_) {
    const size_t ro = (size_t)M_ * T_ * D_ + i;
    if (f32) ((float*)out)[ro] = 0.f;
    else     ((__hip_bfloat16*)out)[ro] = __float2bfloat16(0.f);
  }
}

// ---------------------------------------------------------------------------
// Persistent RK4 integrator. 128 blocks x 512 threads (8 waves). Each block
// owns 16 rows and runs all 49 steps x 4 stages x 3 layers with only
// __syncthreads() between layers. Weights (pre-transposed [N][K] bf16) are
// read straight from global (L2-resident, 3 MB total) into B-fragments.
// Activations + fp32 RK4 state live in LDS (~124 KB, 1 block/CU).
// Wave w owns N-columns [w*128, w*128+128) for L1/L2 and [w*32, w*32+32) for L3.
// MFMA conventions (verified in round 2): A[m=lane&15][k=quad*8+j],
// B[n=lane&15][k=quad*8+j], C col=lane&15, row=quad*4+reg.
// ---------------------------------------------------------------------------
__global__ __launch_bounds__(512, 2) void ode_persist(
    const void* __restrict__ fp_raw, void* __restrict__ out,
    const __hip_bfloat16* __restrict__ W1t,
    const __hip_bfloat16* __restrict__ W2t,
    const __hip_bfloat16* __restrict__ W3t,
    const float* __restrict__ bf1, const float* __restrict__ bf2,
    const float* __restrict__ bf3,
    const float* __restrict__ dts, const int* __restrict__ flags) {
  // LDS: 3*16K (fp32 state) + 8448 (u) + 2*33024 (h1,h2) = 123648 B
  __shared__ float y[16 * 256];
  __shared__ float kcur[16 * 256];
  __shared__ float kacc[16 * 256];
  __shared__ __hip_bfloat16 ubuf[16 * 264];   // row stride 264 (pad 8)
  __shared__ __hip_bfloat16 h1[16 * 1032];    // row stride 1032 (pad 8)
  __shared__ __hip_bfloat16 h2[16 * 1032];

  const int tid = threadIdx.x;
  const int wave = tid >> 6, lane = tid & 63;
  const int quad = lane >> 4, l16 = lane & 15;
  const int m0 = blockIdx.x * 16;
  const int ofl = flags[0];

  // ---- prologue: load y rows from first_point, write t=0 traj, zero k ----
  for (int i = tid; i < 16 * 256; i += 512) {
    const int r = i >> 8, c = i & 255;
    const size_t gi = (size_t)(m0 + r) * 256 + c;
    const float v = ofl ? ((const float*)fp_raw)[gi]
                        : __bfloat162float(((const __hip_bfloat16*)fp_raw)[gi]);
    y[i] = v; kcur[i] = 0.f; kacc[i] = 0.f;
    const size_t o = (size_t)((m0 + r) * T_) * D_ + c;
    if (ofl) ((float*)out)[o] = v;
    else     ((__hip_bfloat16*)out)[o] = __float2bfloat16(v);
  }
  // biases into registers
  float bia1[8], bia2[8], bia3[2];
  #pragma unroll
  for (int ni = 0; ni < 8; ni++) {
    bia1[ni] = bf1[wave * 128 + ni * 16 + l16];
    bia2[ni] = bf2[wave * 128 + ni * 16 + l16];
  }
  bia3[0] = bf3[wave * 32 + l16];
  bia3[1] = bf3[wave * 32 + 16 + l16];
  __syncthreads();

  #pragma unroll 1
  for (int st = 0; st < T_ - 1; ++st) {
    const float dtv = dts[st];
    #pragma unroll 1
    for (int stage = 0; stage < 4; ++stage) {
      const float cc = (stage == 0) ? 0.f : ((stage == 3) ? 1.f : 0.5f);
      const float cdt = cc * dtv;

      // ---- build u = bf16(y + cdt*k_prev) ----
      {
        const int i0 = tid * 8;                 // 4096 elems / 512 threads
        const int row = i0 >> 8, col = i0 & 255;
        const float4 ya = *(const float4*)&y[i0];
        const float4 yb = *(const float4*)&y[i0 + 4];
        const float4 ka = *(const float4*)&kcur[i0];
        const float4 kb = *(const float4*)&kcur[i0 + 4];
        u16x8 pk;
        pk[0] = __builtin_bit_cast(unsigned short, __float2bfloat16(ya.x + cdt * ka.x));
        pk[1] = __builtin_bit_cast(unsigned short, __float2bfloat16(ya.y + cdt * ka.y));
        pk[2] = __builtin_bit_cast(unsigned short, __float2bfloat16(ya.z + cdt * ka.z));
        pk[3] = __builtin_bit_cast(unsigned short, __float2bfloat16(ya.w + cdt * ka.w));
        pk[4] = __builtin_bit_cast(unsigned short, __float2bfloat16(yb.x + cdt * kb.x));
        pk[5] = __builtin_bit_cast(unsigned short, __float2bfloat16(yb.y + cdt * kb.y));
        pk[6] = __builtin_bit_cast(unsigned short, __float2bfloat16(yb.z + cdt * kb.z));
        pk[7] = __builtin_bit_cast(unsigned short, __float2bfloat16(yb.w + cdt * kb.w));
        *(u16x8*)&ubuf[row * 264 + col] = pk;
      }
      __syncthreads();

      // ---- L1: h1 = tanh(u @ W1 + b1), K=256, 8 n-tiles per wave ----
      {
        f32x4 acc[8];
        #pragma unroll
        for (int ni = 0; ni < 8; ni++) acc[ni] = f32x4{0.f, 0.f, 0.f, 0.f};
        #pragma unroll 2
        for (int k0 = 0; k0 < 256; k0 += 32) {
          const bf16x8 aF = *(const bf16x8*)&ubuf[l16 * 264 + k0 + quad * 8];
          #pragma unroll
          for (int ni = 0; ni < 8; ni++) {
            const bf16x8 bF = *(const bf16x8*)&W1t[
                (size_t)(wave * 128 + ni * 16 + l16) * 256 + k0 + quad * 8];
            acc[ni] = __builtin_amdgcn_mfma_f32_16x16x32_bf16(aF, bF, acc[ni], 0, 0, 0);
          }
        }
        #pragma unroll
        for (int ni = 0; ni < 8; ni++) {
          const int gn = wave * 128 + ni * 16 + l16;
          #pragma unroll
          for (int r = 0; r < 4; r++)
            h1[(quad * 4 + r) * 1032 + gn] =
                __float2bfloat16(fast_tanh(acc[ni][r] + bia1[ni]));
        }
      }
      __syncthreads();

      // ---- L2: h2 = tanh(h1 @ W2 + b2), K=1024, 8 n-tiles per wave ----
      {
        f32x4 acc[8];
        #pragma unroll
        for (int ni = 0; ni < 8; ni++) acc[ni] = f32x4{0.f, 0.f, 0.f, 0.f};
        #pragma unroll 2
        for (int k0 = 0; k0 < 1024; k0 += 32) {
          const bf16x8 aF = *(const bf16x8*)&h1[l16 * 1032 + k0 + quad * 8];
          #pragma unroll
          for (int ni = 0; ni < 8; ni++) {
            const bf16x8 bF = *(const bf16x8*)&W2t[
                (size_t)(wave * 128 + ni * 16 + l16) * 1024 + k0 + quad * 8];
            acc[ni] = __builtin_amdgcn_mfma_f32_16x16x32_bf16(aF, bF, acc[ni], 0, 0, 0);
          }
        }
        #pragma unroll
        for (int ni = 0; ni < 8; ni++) {
          const int gn = wave * 128 + ni * 16 + l16;
          #pragma unroll
          for (int r = 0; r < 4; r++)
            h2[(quad * 4 + r) * 1032 + gn] =
                __float2bfloat16(fast_tanh(acc[ni][r] + bia2[ni]));
        }
      }
      __syncthreads();

      // ---- L3: k = h2 @ W3 + b3, K=1024, 2 n-tiles per wave + RK4 update --
      {
        f32x4 acc[2];
        acc[0] = f32x4{0.f, 0.f, 0.f, 0.f};
        acc[1] = f32x4{0.f, 0.f, 0.f, 0.f};
        #pragma unroll 4
        for (int k0 = 0; k0 < 1024; k0 += 32) {
          const bf16x8 aF = *(const bf16x8*)&h2[l16 * 1032 + k0 + quad * 8];
          #pragma unroll
          for (int ni = 0; ni < 2; ni++) {
            const bf16x8 bF = *(const bf16x8*)&W3t[
                (size_t)(wave * 32 + ni * 16 + l16) * 1024 + k0 + quad * 8];
            acc[ni] = __builtin_amdgcn_mfma_f32_16x16x32_bf16(aF, bF, acc[ni], 0, 0, 0);
          }
        }
        #pragma unroll
        for (int ni = 0; ni < 2; ni++) {
          const int col = wave * 32 + ni * 16 + l16;
          #pragma unroll
          for (int r = 0; r < 4; r++) {
            const int row = quad * 4 + r;
            const int idx = row * 256 + col;
            const float v = acc[ni][r] + bia3[ni];
            if (stage < 3) {
              kcur[idx] = v;
              kacc[idx] = (stage == 0) ? v : kacc[idx] + 2.f * v;
            } else {
              const float yv = y[idx] + (dtv * (1.f / 6.f)) * (kacc[idx] + v);
              y[idx] = yv;
              const size_t o = (size_t)((m0 + row) * T_ + st + 1) * D_ + col;
              if (ofl) ((float*)out)[o] = yv;
              else     ((__hip_bfloat16*)out)[o] = __float2bfloat16(yv);
            }
          }
        }
      }
      __syncthreads();
    }
  }
}

// ---------------------------------------------------------------------------
extern "C" void kernel_launch(void* const* d_in, const int* in_sizes, int n_in,
                              void* d_out, int out_size, void* d_ws, size_t ws_size,
                              hipStream_t stream) {
  const void* fp   = d_in[0];
  const void* tarr = d_in[1];
  const void* W1   = d_in[2];
  const void* b1   = d_in[3];
  const void* W2   = d_in[4];
  const void* b2   = d_in[5];
  const void* W3   = d_in[6];
  const void* b3   = d_in[7];

  // workspace carve (~3.2 MB)
  char* ws = (char*)d_ws;
  float* bf1  = (float*)ws;                  ws += (size_t)H_ * 4;
  float* bf2  = (float*)ws;                  ws += (size_t)H_ * 4;
  float* bf3  = (float*)ws;                  ws += (size_t)D_ * 4;
  float* dts  = (float*)ws;                  ws += 64 * 4;
  int*   flags= (int*)ws;                    ws += 64 * 4;
  __hip_bfloat16* W1t = (__hip_bfloat16*)ws; ws += (size_t)H_ * D_ * 2;
  __hip_bfloat16* W2t = (__hip_bfloat16*)ws; ws += (size_t)H_ * H_ * 2;
  __hip_bfloat16* W3t = (__hip_bfloat16*)ws; ws += (size_t)D_ * H_ * 2;

  detect_k<<<1, 64, 0, stream>>>(tarr, W2, dts, flags);
  dim3 tb(32, 8);
  transpose_k<<<dim3(H_ / 32, D_ / 32), tb, 0, stream>>>(W1, W1t, D_, H_, flags);
  transpose_k<<<dim3(H_ / 32, H_ / 32), tb, 0, stream>>>(W2, W2t, H_, H_, flags);
  transpose_k<<<dim3(D_ / 32, H_ / 32), tb, 0, stream>>>(W3, W3t, H_, D_, flags);
  prep_bias_k<<<H_ / 256, 256, 0, stream>>>(b1, b2, b3, bf1, bf2, bf3, d_out, flags);

  ode_persist<<<M_ / 16, 512, 0, stream>>>(fp, d_out, W1t, W2t, W3t,
                                           bf1, bf2, bf3, dts, flags);
}